// Round 4
// baseline (1221.871 us; speedup 1.0000x reference)
//
#include <hip/hip_runtime.h>

#define S_LEN 4096
#define D_DIM 64
#define NBH   64   // B*H = 4*16
#define EPS_F 1e-6f
#define PSZ   (D_DIM * D_DIM + D_DIM)   // 4160 floats per block partial (KV + ksum)

__device__ __forceinline__ float phi_f(float x) {
    // elu(x)+1 == x>0 ? x+1 : exp(x)
    return x > 0.0f ? x + 1.0f : __expf(x);
}

// ---------------------------------------------------------------------------
// Mask dtype detector (see round-1 notes): classifies bool buffer encoding.
// ---------------------------------------------------------------------------
__global__ void detect_mask(const unsigned int* __restrict__ w,
                            unsigned int* __restrict__ flag) {
    __shared__ int all01, allf;
    if (threadIdx.x == 0) { all01 = 1; allf = 1; }
    __syncthreads();
    int a = 1, f = 1;
    for (int i = threadIdx.x; i < 4096; i += blockDim.x) {
        unsigned int v = w[i];
        if (v > 1u) a = 0;
        if (v != 0u && v != 0x3F800000u) f = 0;
    }
    if (!a) atomicExch(&all01, 0);
    if (!f) atomicExch(&allf, 0);
    __syncthreads();
    if (threadIdx.x == 0) *flag = all01 ? 0u : (allf ? 2u : 1u);
}

// ---------------------------------------------------------------------------
// Phase 1: per-block partial KV[d][f] += phi(K)[s,d]*V[s,f] (masked) + ksum.
// T3-lite 2-phase pipeline: double-buffered LDS, ONE barrier per 32-row tile.
//   loop: issue loads(t+1) -> compute buf[cur] -> xform+write buf[cur^1] -> bar
// LDS 33 KB -> 4 blocks/CU; __launch_bounds__(256,4) keeps VGPR <= 128.
// ---------------------------------------------------------------------------
__global__ __launch_bounds__(256, 4) void la_phase1(
    const float* __restrict__ K, const float* __restrict__ V,
    const void* __restrict__ mask, const unsigned int* __restrict__ flagp,
    float* __restrict__ partials, int CH)
{
    __shared__ float smem[2][4096];   // [buf][ k:0..2048 | v:2048..4096 ]
    __shared__ float ksred[4][64];

    const int bh   = blockIdx.x;
    const int b    = bh >> 4;             // H = 16
    const unsigned int flag = *flagp;
    const int tid  = threadIdx.x;
    const int wave = tid >> 6;
    const int lane = tid & 63;
    const int tt   = lane >> 3;           // d-octet
    const int tf   = lane & 7;            // f-octet
    const int chunk = S_LEN / CH;
    const int NT    = chunk / 32;
    const int s0    = blockIdx.y * chunk;

    const float* Kbh = K + (size_t)bh * S_LEN * D_DIM;
    const float* Vbh = V + (size_t)bh * S_LEN * D_DIM;
    const int*           mi = (const int*)mask;
    const unsigned char* mb = (const unsigned char*)mask;
    const float*         mf = (const float*)mask;

    float acc[8][8];
    float ks[8];
    #pragma unroll
    for (int i = 0; i < 8; ++i) {
        ks[i] = 0.0f;
        #pragma unroll
        for (int j = 0; j < 8; ++j) acc[i][j] = 0.0f;
    }

    const int row0 = tid >> 4;            // 0..15 (p adds 16)
    const int col0 = (tid & 15) * 4;

    float4 kr[2], vr[2];
    int    pr[2];

    auto issue = [&](int ts) {
        #pragma unroll
        for (int p = 0; p < 2; ++p) {
            int row = p * 16 + row0;
            int s   = s0 + ts + row;
            int ml  = b * S_LEN + s;
            bool pad;
            if (flag == 0u)      pad = (mi[ml] != 0);
            else if (flag == 1u) pad = (mb[ml] != 0);
            else                 pad = (mf[ml] != 0.0f);
            pr[p] = pad ? 1 : 0;
            kr[p] = *reinterpret_cast<const float4*>(&Kbh[(size_t)s * D_DIM + col0]);
            vr[p] = *reinterpret_cast<const float4*>(&Vbh[(size_t)s * D_DIM + col0]);
        }
    };

    auto xstore = [&](int bufi) {
        #pragma unroll
        for (int p = 0; p < 2; ++p) {
            int row = p * 16 + row0;
            float4 k4 = kr[p], v4 = vr[p];
            if (pr[p]) {
                k4 = make_float4(0.f, 0.f, 0.f, 0.f);
                v4 = make_float4(0.f, 0.f, 0.f, 0.f);
            } else {
                k4.x = phi_f(k4.x); k4.y = phi_f(k4.y);
                k4.z = phi_f(k4.z); k4.w = phi_f(k4.w);
            }
            *reinterpret_cast<float4*>(&smem[bufi][row * 64 + col0])        = k4;
            *reinterpret_cast<float4*>(&smem[bufi][2048 + row * 64 + col0]) = v4;
        }
    };

    issue(0);
    xstore(0);
    __syncthreads();
    int cur = 0;
    for (int it = 0; it < NT; ++it) {
        if (it + 1 < NT) issue((it + 1) * 32);
        #pragma unroll
        for (int r = 0; r < 8; ++r) {
            const int row = wave * 8 + r;
            float kk[8], vv[8];
            *reinterpret_cast<float4*>(&kk[0]) = *reinterpret_cast<const float4*>(&smem[cur][row * 64 + tt * 8]);
            *reinterpret_cast<float4*>(&kk[4]) = *reinterpret_cast<const float4*>(&smem[cur][row * 64 + tt * 8 + 4]);
            *reinterpret_cast<float4*>(&vv[0]) = *reinterpret_cast<const float4*>(&smem[cur][2048 + row * 64 + tf * 8]);
            *reinterpret_cast<float4*>(&vv[4]) = *reinterpret_cast<const float4*>(&smem[cur][2048 + row * 64 + tf * 8 + 4]);
            #pragma unroll
            for (int i = 0; i < 8; ++i) {
                #pragma unroll
                for (int j = 0; j < 8; ++j)
                    acc[i][j] = fmaf(kk[i], vv[j], acc[i][j]);
                ks[i] += kk[i];
            }
        }
        if (it + 1 < NT) xstore(cur ^ 1);
        __syncthreads();
        cur ^= 1;
    }

    // ---- cross-wave reduction through LDS (reuse smem[0]), then one store ----
    if (tf == 0) {
        #pragma unroll
        for (int i = 0; i < 8; ++i) ksred[wave][tt * 8 + i] = ks[i];
    }
    for (int w = 0; w < 4; ++w) {
        if (wave == w) {
            #pragma unroll
            for (int i = 0; i < 8; ++i) {
                float4* p0 = reinterpret_cast<float4*>(&smem[0][(tt * 8 + i) * 64 + tf * 8]);
                float4 a0 = make_float4(acc[i][0], acc[i][1], acc[i][2], acc[i][3]);
                float4 a1 = make_float4(acc[i][4], acc[i][5], acc[i][6], acc[i][7]);
                if (w == 0) { p0[0] = a0; p0[1] = a1; }
                else {
                    float4 c0 = p0[0], c1 = p0[1];
                    c0.x += a0.x; c0.y += a0.y; c0.z += a0.z; c0.w += a0.w;
                    c1.x += a1.x; c1.y += a1.y; c1.z += a1.z; c1.w += a1.w;
                    p0[0] = c0; p0[1] = c1;
                }
            }
        }
        __syncthreads();
    }

    float* pp = partials + ((size_t)(bh * CH + blockIdx.y)) * PSZ;
    #pragma unroll
    for (int q = 0; q < 4; ++q) {
        int fi = q * 256 + tid;           // float4 idx 0..1023
        reinterpret_cast<float4*>(pp)[fi] = reinterpret_cast<const float4*>(&smem[0][0])[fi];
    }
    if (tid < 64)
        pp[4096 + tid] = ksred[0][tid] + ksred[1][tid] + ksred[2][tid] + ksred[3][tid];
}

// ---------------------------------------------------------------------------
// Reduce CH partials per bh into final KV (64x64) and ksum (64).
// ---------------------------------------------------------------------------
__global__ __launch_bounds__(256) void la_reduce(
    const float* __restrict__ partials, float* __restrict__ kv,
    float* __restrict__ ksum, int CH)
{
    const int bh = blockIdx.x;
    const float4* base = reinterpret_cast<const float4*>(partials + (size_t)bh * CH * PSZ);
    for (int idx = threadIdx.x; idx < PSZ / 4; idx += 256) {
        float4 s = make_float4(0.f, 0.f, 0.f, 0.f);
        for (int c = 0; c < CH; ++c) {
            float4 v = base[(size_t)c * (PSZ / 4) + idx];
            s.x += v.x; s.y += v.y; s.z += v.z; s.w += v.w;
        }
        if (idx < 1024)
            reinterpret_cast<float4*>(kv + (size_t)bh * 4096)[idx] = s;
        else
            reinterpret_cast<float4*>(ksum + bh * 64)[idx - 1024] = s;
    }
}

// ---------------------------------------------------------------------------
// Phase 2: out[t] = (phi(q)[t] @ KV) / (phi(q)[t].ksum + eps).
// Occupancy rebuild: NO q LDS (was 32 KB with only 8-way reuse). q loaded
// straight from global (8 tf-lanes broadcast same address; 64B lines reused
// across 4 consecutive dq iters via L1) with 1-iter register prefetch.
// Block 256 = 4 waves, each wave 32 t rows, 4t x 8f per lane (acc=32 VGPR).
// LDS = KV 16 KB + ksum only -> many blocks/CU; launch_bounds caps VGPR @128.
// ---------------------------------------------------------------------------
__global__ __launch_bounds__(256, 4) void la_phase2(
    const float* __restrict__ Q,
    const float* __restrict__ kv_ws, const float* __restrict__ ksum_ws,
    float* __restrict__ out)
{
    __shared__ float kvs[64][64];     // [d][f]
    __shared__ float kss[64];

    const int bh   = blockIdx.x;
    const int tid  = threadIdx.x;     // 0..255
    const int wave = tid >> 6;
    const int lane = tid & 63;
    const int tt   = lane >> 3;       // t-phase (0..7)
    const int tf   = lane & 7;        // f-octet
    const int t0   = blockIdx.y * 128 + wave * 32;   // wave's rows: t0+tt+8r

    const float* Qbh = Q + (size_t)bh * S_LEN * D_DIM;
    const float* kvb = kv_ws + (size_t)bh * D_DIM * D_DIM;

    // stage KV (4096 floats) + ksum
    #pragma unroll
    for (int p = 0; p < 4; ++p) {
        int fi = p * 256 + tid;       // float4 idx 0..1023
        reinterpret_cast<float4*>(kvs)[fi] = reinterpret_cast<const float4*>(kvb)[fi];
    }
    if (tid < 16)
        reinterpret_cast<float4*>(kss)[tid] =
            reinterpret_cast<const float4*>(ksum_ws + bh * D_DIM)[tid];
    __syncthreads();

    const float* qr0 = Qbh + (size_t)(t0 + tt) * D_DIM;   // row r at +r*8*64

    float acc[4][8];
    float z[4];
    #pragma unroll
    for (int r = 0; r < 4; ++r) {
        z[r] = 0.0f;
        #pragma unroll
        for (int c = 0; c < 8; ++c) acc[r][c] = 0.0f;
    }

    float4 qn[4];
    #pragma unroll
    for (int r = 0; r < 4; ++r)
        qn[r] = *reinterpret_cast<const float4*>(qr0 + r * 8 * D_DIM);

    #pragma unroll 4
    for (int dq = 0; dq < 64; dq += 4) {
        float qc[4][4];
        #pragma unroll
        for (int r = 0; r < 4; ++r) {
            qc[r][0] = phi_f(qn[r].x); qc[r][1] = phi_f(qn[r].y);
            qc[r][2] = phi_f(qn[r].z); qc[r][3] = phi_f(qn[r].w);
        }
        if (dq + 4 < 64) {
            #pragma unroll
            for (int r = 0; r < 4; ++r)
                qn[r] = *reinterpret_cast<const float4*>(qr0 + r * 8 * D_DIM + dq + 4);
        }
        float ks4[4];
        *reinterpret_cast<float4*>(ks4) = *reinterpret_cast<const float4*>(&kss[dq]);
        #pragma unroll
        for (int j = 0; j < 4; ++j) {
            float kvr[8];
            *reinterpret_cast<float4*>(&kvr[0]) = *reinterpret_cast<const float4*>(&kvs[dq + j][tf * 8]);
            *reinterpret_cast<float4*>(&kvr[4]) = *reinterpret_cast<const float4*>(&kvs[dq + j][tf * 8 + 4]);
            #pragma unroll
            for (int r = 0; r < 4; ++r) {
                z[r] = fmaf(qc[r][j], ks4[j], z[r]);
                #pragma unroll
                for (int c = 0; c < 8; ++c)
                    acc[r][c] = fmaf(qc[r][j], kvr[c], acc[r][c]);
            }
        }
    }

    #pragma unroll
    for (int r = 0; r < 4; ++r) {
        int t = t0 + tt + 8 * r;
        float inv = 1.0f / (z[r] + EPS_F);
        float o[8];
        #pragma unroll
        for (int c = 0; c < 8; ++c) o[c] = acc[r][c] * inv;
        float* op = out + ((size_t)bh * S_LEN + t) * D_DIM + tf * 8;
        *reinterpret_cast<float4*>(&op[0]) = *reinterpret_cast<const float4*>(&o[0]);
        *reinterpret_cast<float4*>(&op[4]) = *reinterpret_cast<const float4*>(&o[4]);
    }
}

// ---------------------------------------------------------------------------
extern "C" void kernel_launch(void* const* d_in, const int* in_sizes, int n_in,
                              void* d_out, int out_size, void* d_ws, size_t ws_size,
                              hipStream_t stream)
{
    (void)in_sizes; (void)n_in; (void)out_size;
    const float* Q   = (const float*)d_in[0];
    const float* K   = (const float*)d_in[1];
    const float* V   = (const float*)d_in[2];
    const void* mask = d_in[3];

    // ws layout: partials[NBH*CH*PSZ] | kv[NBH*4096] | ksum[NBH*64] | flag
    int CH = 16;
    while (CH > 1) {
        size_t need = ((size_t)NBH * CH * PSZ + (size_t)NBH * 4096 + NBH * 64) * 4 + 16;
        if (need <= ws_size) break;
        CH >>= 1;
    }
    float* partials = (float*)d_ws;
    float* kvf  = partials + (size_t)NBH * CH * PSZ;
    float* ksf  = kvf + (size_t)NBH * 4096;
    unsigned int* flag = (unsigned int*)(ksf + NBH * 64);

    detect_mask<<<1, 256, 0, stream>>>((const unsigned int*)mask, flag);
    la_phase1<<<dim3(NBH, CH), 256, 0, stream>>>(K, V, mask, flag, partials, CH);
    la_reduce<<<NBH, 256, 0, stream>>>(partials, kvf, ksf, CH);
    la_phase2<<<dim3(NBH, 32), 256, 0, stream>>>(Q, kvf, ksf, (float*)d_out);
}

// Round 9
// 281.683 us; speedup vs baseline: 4.3378x; 4.3378x over previous
//
#include <hip/hip_runtime.h>

#define S_LEN 4096
#define D_DIM 64
#define NBH   64   // B*H = 4*16
#define EPS_F 1e-6f
#define PSZ   (D_DIM * D_DIM + D_DIM)   // 4160 floats per block partial (KV + ksum)

__device__ __forceinline__ float phi_f(float x) {
    // elu(x)+1 == x>0 ? x+1 : exp(x)
    return x > 0.0f ? x + 1.0f : __expf(x);
}

// ---------------------------------------------------------------------------
// Mask dtype detector (see round-1 notes): classifies bool buffer encoding.
// ---------------------------------------------------------------------------
__global__ void detect_mask(const unsigned int* __restrict__ w,
                            unsigned int* __restrict__ flag) {
    __shared__ int all01, allf;
    if (threadIdx.x == 0) { all01 = 1; allf = 1; }
    __syncthreads();
    int a = 1, f = 1;
    for (int i = threadIdx.x; i < 4096; i += blockDim.x) {
        unsigned int v = w[i];
        if (v > 1u) a = 0;
        if (v != 0u && v != 0x3F800000u) f = 0;
    }
    if (!a) atomicExch(&all01, 0);
    if (!f) atomicExch(&allf, 0);
    __syncthreads();
    if (threadIdx.x == 0) *flag = all01 ? 0u : (allf ? 2u : 1u);
}

// ---------------------------------------------------------------------------
// Phase 1: per-block partial KV[d][f] += phi(K)[s,d]*V[s,f] (masked) + ksum.
// Double-buffered LDS, ONE barrier per 32-row tile:
//   loop: issue loads(t+1) -> compute buf[cur] -> xform+write buf[cur^1] -> bar
// NOTE: __launch_bounds__(256) ONLY — round 4 proved (256,4) forces VGPR=64
// and spills acc[8][8] to scratch (2.4 GB HBM traffic, 8x slowdown).
// ---------------------------------------------------------------------------
__global__ __launch_bounds__(256) void la_phase1(
    const float* __restrict__ K, const float* __restrict__ V,
    const void* __restrict__ mask, const unsigned int* __restrict__ flagp,
    float* __restrict__ partials, int CH)
{
    __shared__ float smem[2][4096];   // [buf][ k:0..2048 | v:2048..4096 ]
    __shared__ float ksred[4][64];

    const int bh   = blockIdx.x;
    const int b    = bh >> 4;             // H = 16
    const unsigned int flag = *flagp;
    const int tid  = threadIdx.x;
    const int wave = tid >> 6;
    const int lane = tid & 63;
    const int tt   = lane >> 3;           // d-octet
    const int tf   = lane & 7;            // f-octet
    const int chunk = S_LEN / CH;
    const int NT    = chunk / 32;
    const int s0    = blockIdx.y * chunk;

    const float* Kbh = K + (size_t)bh * S_LEN * D_DIM;
    const float* Vbh = V + (size_t)bh * S_LEN * D_DIM;
    const int*           mi = (const int*)mask;
    const unsigned char* mb = (const unsigned char*)mask;
    const float*         mf = (const float*)mask;

    float acc[8][8];
    float ks[8];
    #pragma unroll
    for (int i = 0; i < 8; ++i) {
        ks[i] = 0.0f;
        #pragma unroll
        for (int j = 0; j < 8; ++j) acc[i][j] = 0.0f;
    }

    const int row0 = tid >> 4;            // 0..15 (p adds 16)
    const int col0 = (tid & 15) * 4;

    float4 kr[2], vr[2];
    int    pr[2];

    auto issue = [&](int ts) {
        #pragma unroll
        for (int p = 0; p < 2; ++p) {
            int row = p * 16 + row0;
            int s   = s0 + ts + row;
            int ml  = b * S_LEN + s;
            bool pad;
            if (flag == 0u)      pad = (mi[ml] != 0);
            else if (flag == 1u) pad = (mb[ml] != 0);
            else                 pad = (mf[ml] != 0.0f);
            pr[p] = pad ? 1 : 0;
            kr[p] = *reinterpret_cast<const float4*>(&Kbh[(size_t)s * D_DIM + col0]);
            vr[p] = *reinterpret_cast<const float4*>(&Vbh[(size_t)s * D_DIM + col0]);
        }
    };

    auto xstore = [&](int bufi) {
        #pragma unroll
        for (int p = 0; p < 2; ++p) {
            int row = p * 16 + row0;
            float4 k4 = kr[p], v4 = vr[p];
            if (pr[p]) {
                k4 = make_float4(0.f, 0.f, 0.f, 0.f);
                v4 = make_float4(0.f, 0.f, 0.f, 0.f);
            } else {
                k4.x = phi_f(k4.x); k4.y = phi_f(k4.y);
                k4.z = phi_f(k4.z); k4.w = phi_f(k4.w);
            }
            *reinterpret_cast<float4*>(&smem[bufi][row * 64 + col0])        = k4;
            *reinterpret_cast<float4*>(&smem[bufi][2048 + row * 64 + col0]) = v4;
        }
    };

    issue(0);
    xstore(0);
    __syncthreads();
    int cur = 0;
    for (int it = 0; it < NT; ++it) {
        if (it + 1 < NT) issue((it + 1) * 32);
        #pragma unroll
        for (int r = 0; r < 8; ++r) {
            const int row = wave * 8 + r;
            float kk[8], vv[8];
            *reinterpret_cast<float4*>(&kk[0]) = *reinterpret_cast<const float4*>(&smem[cur][row * 64 + tt * 8]);
            *reinterpret_cast<float4*>(&kk[4]) = *reinterpret_cast<const float4*>(&smem[cur][row * 64 + tt * 8 + 4]);
            *reinterpret_cast<float4*>(&vv[0]) = *reinterpret_cast<const float4*>(&smem[cur][2048 + row * 64 + tf * 8]);
            *reinterpret_cast<float4*>(&vv[4]) = *reinterpret_cast<const float4*>(&smem[cur][2048 + row * 64 + tf * 8 + 4]);
            #pragma unroll
            for (int i = 0; i < 8; ++i) {
                #pragma unroll
                for (int j = 0; j < 8; ++j)
                    acc[i][j] = fmaf(kk[i], vv[j], acc[i][j]);
                ks[i] += kk[i];
            }
        }
        if (it + 1 < NT) xstore(cur ^ 1);
        __syncthreads();
        cur ^= 1;
    }

    // ---- cross-wave reduction through LDS (reuse smem[0]), then one store ----
    if (tf == 0) {
        #pragma unroll
        for (int i = 0; i < 8; ++i) ksred[wave][tt * 8 + i] = ks[i];
    }
    for (int w = 0; w < 4; ++w) {
        if (wave == w) {
            #pragma unroll
            for (int i = 0; i < 8; ++i) {
                float4* p0 = reinterpret_cast<float4*>(&smem[0][(tt * 8 + i) * 64 + tf * 8]);
                float4 a0 = make_float4(acc[i][0], acc[i][1], acc[i][2], acc[i][3]);
                float4 a1 = make_float4(acc[i][4], acc[i][5], acc[i][6], acc[i][7]);
                if (w == 0) { p0[0] = a0; p0[1] = a1; }
                else {
                    float4 c0 = p0[0], c1 = p0[1];
                    c0.x += a0.x; c0.y += a0.y; c0.z += a0.z; c0.w += a0.w;
                    c1.x += a1.x; c1.y += a1.y; c1.z += a1.z; c1.w += a1.w;
                    p0[0] = c0; p0[1] = c1;
                }
            }
        }
        __syncthreads();
    }

    float* pp = partials + ((size_t)(bh * CH + blockIdx.y)) * PSZ;
    #pragma unroll
    for (int q = 0; q < 4; ++q) {
        int fi = q * 256 + tid;           // float4 idx 0..1023
        reinterpret_cast<float4*>(pp)[fi] = reinterpret_cast<const float4*>(&smem[0][0])[fi];
    }
    if (tid < 64)
        pp[4096 + tid] = ksred[0][tid] + ksred[1][tid] + ksred[2][tid] + ksred[3][tid];
}

// ---------------------------------------------------------------------------
// Reduce CH partials per bh into final KV (64x64) and ksum (64).
// ROUND-8 BUG FIX: the k<2 trip count covered only idx 0..511 / 520..1031 per
// half, leaving f4 512..519 (KV) and 1032..1039 (ksum[32..63]) POISONED ->
// absmax 0.144. Plain strided loop now covers all 520 f4 per half.
// ---------------------------------------------------------------------------
template <int CHT>
__global__ __launch_bounds__(256) void la_reduce_t(
    const float* __restrict__ partials, float* __restrict__ kv,
    float* __restrict__ ksum)
{
    const int bh = blockIdx.x;
    const int half = blockIdx.y;                 // 0..1, each covers 520 f4
    const float4* base = reinterpret_cast<const float4*>(partials + (size_t)bh * CHT * PSZ);
    const int hi = (half + 1) * 520;             // PSZ/4 = 1040 total
    for (int idx = half * 520 + threadIdx.x; idx < hi; idx += 256) {
        float4 s = make_float4(0.f, 0.f, 0.f, 0.f);
        #pragma unroll
        for (int c = 0; c < CHT; ++c) {
            float4 v = base[(size_t)c * (PSZ / 4) + idx];
            s.x += v.x; s.y += v.y; s.z += v.z; s.w += v.w;
        }
        if (idx < 1024)
            reinterpret_cast<float4*>(kv + (size_t)bh * 4096)[idx] = s;
        else
            reinterpret_cast<float4*>(ksum + bh * 64)[idx - 1024] = s;
    }
}

// ---------------------------------------------------------------------------
// Phase 2: out[t] = (phi(q)[t] @ KV) / (phi(q)[t].ksum + eps).
// No q LDS (32 KB of LDS for 8-way reuse strangled occupancy in round 3).
// q loaded straight from global (8 tf-lanes broadcast same line, L1-served)
// with branch-free 1-iter register prefetch. Block 256 = 4 waves, 4t x 8f
// per lane. LDS = 16.6 KB. Plain __launch_bounds__(256) — no VGPR cap.
// ---------------------------------------------------------------------------
__global__ __launch_bounds__(256) void la_phase2(
    const float* __restrict__ Q,
    const float* __restrict__ kv_ws, const float* __restrict__ ksum_ws,
    float* __restrict__ out)
{
    __shared__ float kvs[64][64];     // [d][f]
    __shared__ float kss[64];

    const int bh   = blockIdx.x;
    const int tid  = threadIdx.x;     // 0..255
    const int wave = tid >> 6;
    const int lane = tid & 63;
    const int tt   = lane >> 3;       // t-phase (0..7)
    const int tf   = lane & 7;        // f-octet
    const int t0   = blockIdx.y * 128 + wave * 32;   // wave's rows: t0+tt+8r

    const float* Qbh = Q + (size_t)bh * S_LEN * D_DIM;
    const float* kvb = kv_ws + (size_t)bh * D_DIM * D_DIM;

    // stage KV (4096 floats) + ksum
    #pragma unroll
    for (int p = 0; p < 4; ++p) {
        int fi = p * 256 + tid;       // float4 idx 0..1023
        reinterpret_cast<float4*>(kvs)[fi] = reinterpret_cast<const float4*>(kvb)[fi];
    }
    if (tid < 16)
        reinterpret_cast<float4*>(kss)[tid] =
            reinterpret_cast<const float4*>(ksum_ws + bh * D_DIM)[tid];
    __syncthreads();

    const float* qr0 = Qbh + (size_t)(t0 + tt) * D_DIM;   // row r at +r*8*64

    float acc[4][8];
    float z[4];
    #pragma unroll
    for (int r = 0; r < 4; ++r) {
        z[r] = 0.0f;
        #pragma unroll
        for (int c = 0; c < 8; ++c) acc[r][c] = 0.0f;
    }

    float4 qn[4];
    #pragma unroll
    for (int r = 0; r < 4; ++r)
        qn[r] = *reinterpret_cast<const float4*>(qr0 + r * 8 * D_DIM);

    #pragma unroll 4
    for (int dq = 0; dq < 64; dq += 4) {
        float qc[4][4];
        #pragma unroll
        for (int r = 0; r < 4; ++r) {
            qc[r][0] = phi_f(qn[r].x); qc[r][1] = phi_f(qn[r].y);
            qc[r][2] = phi_f(qn[r].z); qc[r][3] = phi_f(qn[r].w);
        }
        const int dnext = (dq + 4) & 63;   // wraps to 0 on last iter: in-bounds, unused
        #pragma unroll
        for (int r = 0; r < 4; ++r)
            qn[r] = *reinterpret_cast<const float4*>(qr0 + r * 8 * D_DIM + dnext);
        float ks4[4];
        *reinterpret_cast<float4*>(ks4) = *reinterpret_cast<const float4*>(&kss[dq]);
        #pragma unroll
        for (int j = 0; j < 4; ++j) {
            float kvr[8];
            *reinterpret_cast<float4*>(&kvr[0]) = *reinterpret_cast<const float4*>(&kvs[dq + j][tf * 8]);
            *reinterpret_cast<float4*>(&kvr[4]) = *reinterpret_cast<const float4*>(&kvs[dq + j][tf * 8 + 4]);
            #pragma unroll
            for (int r = 0; r < 4; ++r) {
                z[r] = fmaf(qc[r][j], ks4[j], z[r]);
                #pragma unroll
                for (int c = 0; c < 8; ++c)
                    acc[r][c] = fmaf(qc[r][j], kvr[c], acc[r][c]);
            }
        }
    }

    #pragma unroll
    for (int r = 0; r < 4; ++r) {
        int t = t0 + tt + 8 * r;
        float inv = 1.0f / (z[r] + EPS_F);
        float o[8];
        #pragma unroll
        for (int c = 0; c < 8; ++c) o[c] = acc[r][c] * inv;
        float* op = out + ((size_t)bh * S_LEN + t) * D_DIM + tf * 8;
        *reinterpret_cast<float4*>(&op[0]) = *reinterpret_cast<const float4*>(&o[0]);
        *reinterpret_cast<float4*>(&op[4]) = *reinterpret_cast<const float4*>(&o[4]);
    }
}

// ---------------------------------------------------------------------------
extern "C" void kernel_launch(void* const* d_in, const int* in_sizes, int n_in,
                              void* d_out, int out_size, void* d_ws, size_t ws_size,
                              hipStream_t stream)
{
    (void)in_sizes; (void)n_in; (void)out_size;
    const float* Q   = (const float*)d_in[0];
    const float* K   = (const float*)d_in[1];
    const float* V   = (const float*)d_in[2];
    const void* mask = d_in[3];

    // ws layout: partials[NBH*CH*PSZ] | kv[NBH*4096] | ksum[NBH*64] | flag
    int CH = 16;
    while (CH > 1) {
        size_t need = ((size_t)NBH * CH * PSZ + (size_t)NBH * 4096 + NBH * 64) * 4 + 16;
        if (need <= ws_size) break;
        CH >>= 1;
    }
    float* partials = (float*)d_ws;
    float* kvf  = partials + (size_t)NBH * CH * PSZ;
    float* ksf  = kvf + (size_t)NBH * 4096;
    unsigned int* flag = (unsigned int*)(ksf + NBH * 64);

    detect_mask<<<1, 256, 0, stream>>>((const unsigned int*)mask, flag);
    la_phase1<<<dim3(NBH, CH), 256, 0, stream>>>(K, V, mask, flag, partials, CH);
    switch (CH) {
        case 16: la_reduce_t<16><<<dim3(NBH, 2), 256, 0, stream>>>(partials, kvf, ksf); break;
        case 8:  la_reduce_t<8> <<<dim3(NBH, 2), 256, 0, stream>>>(partials, kvf, ksf); break;
        case 4:  la_reduce_t<4> <<<dim3(NBH, 2), 256, 0, stream>>>(partials, kvf, ksf); break;
        case 2:  la_reduce_t<2> <<<dim3(NBH, 2), 256, 0, stream>>>(partials, kvf, ksf); break;
        default: la_reduce_t<1> <<<dim3(NBH, 2), 256, 0, stream>>>(partials, kvf, ksf); break;
    }
    la_phase2<<<dim3(NBH, 32), 256, 0, stream>>>(Q, kvf, ksf, (float*)d_out);
}